// Round 11
// baseline (73.711 us; speedup 1.0000x reference)
//
#include <hip/hip_runtime.h>

namespace {

typedef float v2f __attribute__((ext_vector_type(2)));
__device__ __forceinline__ v2f mk2(float a, float b) { v2f r; r.x = a; r.y = b; return r; }

constexpr int NB = 4;
constexpr int ND = 128;
constexpr int NH = 192;
constexpr int NW = 192;
constexpr int PLI = NH * NW;
constexpr int CD = 16;    // output planes per block; 128/16 = 8 exact
constexpr int LDSW = 194; // 1 left pad + 192 + 1 right pad

__global__ __launch_bounds__(256, 2)
void edge_loss3d(const float* __restrict__ pred,
                 const float* __restrict__ targ,
                 float* __restrict__ out)
{
    const int lane = threadIdx.x & 63;
    const int wid  = threadIdx.x >> 6;
    const int d0   = blockIdx.x * CD;
    const int h0   = blockIdx.y * 4;          // block's 4 output rows h0..h0+3
    const int b    = blockIdx.z;

    __shared__ float lds[2][6][LDSW];
    __shared__ float zrow[LDSW];
    __shared__ float wsum[4];

    // zero pads + zero-row once (first read is after phase-0 barriers)
    if (threadIdx.x < LDSW) zrow[threadIdx.x] = 0.f;
    if (threadIdx.x < 24) {
        const int t = threadIdx.x / 12, r = (threadIdx.x % 12) / 2, s = threadIdx.x & 1;
        lds[t][r][s * (LDSW - 1)] = 0.f;
    }

    // staging role: wave stages tensor tw, staged rows rbase..rbase+2 (idx 0 <-> h0-1)
    const int tw = wid >> 1;
    const int rbase = (wid & 1) * 3;
    const float* sb = (tw ? targ : pred) + (size_t)b * ND * PLI + 3 * lane;

    // clamped row offsets for staging loads (garbage rows are never read back)
    const int hh0 = h0 - 1 + rbase, hh1 = hh0 + 1, hh2 = hh0 + 2;
    const int ro0 = (hh0 < 0 ? 0 : (hh0 > NH - 1 ? NH - 1 : hh0)) * NW;
    const int ro1 = (hh1 < 0 ? 0 : (hh1 > NH - 1 ? NH - 1 : hh1)) * NW;
    const int ro2 = (hh2 < 0 ? 0 : (hh2 > NH - 1 ? NH - 1 : hh2)) * NW;

    float* ldw = &lds[tw][rbase][1 + 3 * lane];

    // read pointers with zero-row redirect (h-boundary handled here, no masks)
    const bool vlo = (h0 + wid - 1) >= 0;
    const bool vhi = (h0 + wid + 1) < NH;
    const float* zz   = &zrow[1 + 3 * lane];
    const float* ldp0 = vlo ? &lds[0][wid][1 + 3 * lane]     : zz;
    const float* ldp1 =       &lds[0][wid + 1][1 + 3 * lane];
    const float* ldp2 = vhi ? &lds[0][wid + 2][1 + 3 * lane] : zz;
    const float* ldt0 = vlo ? &lds[1][wid][1 + 3 * lane]     : zz;
    const float* ldt1 =       &lds[1][wid + 1][1 + 3 * lane];
    const float* ldt2 = vhi ? &lds[1][wid + 2][1 + 3 * lane] : zz;

    // two in-flight staged planes (2-deep prefetch) + rolling state
    float gA00, gA01, gA02, gA10, gA11, gA12, gA20, gA21, gA22;
    float gB00, gB01, gB02, gB10, gB11, gB12, gB20, gB21, gB22;
    v2f   qa[2][3][3];
    float qc[2][3][3];
    v2f   accA = mk2(0.f, 0.f);
    float acc2 = 0.f;

#define RPTR(T, RR) ((T) ? ((RR) == 0 ? ldt0 : (RR) == 1 ? ldt1 : ldt2)       \
                         : ((RR) == 0 ? ldp0 : (RR) == 1 ? ldp1 : ldp2))

#define PREFETCH(S, P) do {                                                   \
    const int o_ = (P) * PLI;                                                 \
    g##S##00 = sb[o_ + ro0]; g##S##01 = sb[o_ + ro0 + 1]; g##S##02 = sb[o_ + ro0 + 2]; \
    g##S##10 = sb[o_ + ro1]; g##S##11 = sb[o_ + ro1 + 1]; g##S##12 = sb[o_ + ro1 + 2]; \
    g##S##20 = sb[o_ + ro2]; g##S##21 = sb[o_ + ro2 + 1]; g##S##22 = sb[o_ + ro2 + 2]; \
} while (0)

#define PREFETCH_M(S, P) do {                                                 \
    const int pc_ = (P) < 0 ? 0 : ((P) > ND - 1 ? ND - 1 : (P));              \
    const float pm_ = ((P) >= 0 && (P) < ND) ? 1.f : 0.f;                     \
    const int o_ = pc_ * PLI;                                                 \
    g##S##00 = sb[o_ + ro0] * pm_; g##S##01 = sb[o_ + ro0 + 1] * pm_; g##S##02 = sb[o_ + ro0 + 2] * pm_; \
    g##S##10 = sb[o_ + ro1] * pm_; g##S##11 = sb[o_ + ro1 + 1] * pm_; g##S##12 = sb[o_ + ro1 + 2] * pm_; \
    g##S##20 = sb[o_ + ro2] * pm_; g##S##21 = sb[o_ + ro2 + 1] * pm_; g##S##22 = sb[o_ + ro2 + 2] * pm_; \
} while (0)

#define STAGE_WRITE(S) do {                                                   \
    ldw[0] = g##S##00; ldw[1] = g##S##01; ldw[2] = g##S##02;                  \
    ldw[LDSW + 0] = g##S##10; ldw[LDSW + 1] = g##S##11; ldw[LDSW + 2] = g##S##12; \
    ldw[2 * LDSW + 0] = g##S##20; ldw[2 * LDSW + 1] = g##S##21; ldw[2 * LDSW + 2] = g##S##22; \
} while (0)

// one h-row pass of tensor T into slot SP; packed (j0,j1) + scalar j2
#define ROWPASS(T, SP, RR) do {                                               \
    const float* rp_ = RPTR(T, RR);                                           \
    const float xm_ = rp_[-1], x0_ = rp_[0], x1_ = rp_[1], x2_ = rp_[2], xp_ = rp_[3]; \
    const v2f L_ = mk2(xm_, x0_), M_ = mk2(x0_, x1_), R_ = mk2(x1_, x2_);     \
    const v2f   sA_ = (L_ + R_ + 2.f * M_) * 0.25f;                           \
    const float s2_ = (x1_ + xp_ + 2.f * x2_) * 0.25f;                        \
    const v2f   tA_ = R_ - L_;                                                \
    const float t2_ = xp_ - x1_;                                              \
    if ((RR) == 0) {                                                          \
        qa[T][SP][0] = 0.25f * sA_;  qc[T][SP][0] = 0.25f * s2_;              \
        qa[T][SP][1] = -sA_;         qc[T][SP][1] = -s2_;                     \
        qa[T][SP][2] = 0.25f * tA_;  qc[T][SP][2] = 0.25f * t2_;              \
    } else if ((RR) == 1) {                                                   \
        qa[T][SP][0] += 0.5f * sA_;  qc[T][SP][0] += 0.5f * s2_;              \
        /* sobel_h center weight = 0 -> ts unchanged */                       \
        qa[T][SP][2] += 0.5f * tA_;  qc[T][SP][2] += 0.5f * t2_;              \
    } else {                                                                  \
        qa[T][SP][0] += 0.25f * sA_; qc[T][SP][0] += 0.25f * s2_;             \
        qa[T][SP][1] += sA_;         qc[T][SP][1] += s2_;                     \
        qa[T][SP][2] += 0.25f * tA_; qc[T][SP][2] += 0.25f * t2_;             \
    }                                                                         \
} while (0)

// raw barriers: LDS visibility via lgkmcnt(0); global prefetches stay in flight
#define BAR() do {                                                            \
    asm volatile("s_waitcnt lgkmcnt(0)" ::: "memory");                        \
    __builtin_amdgcn_s_barrier();                                             \
} while (0)

// phase: stage set S (plane fetched 2 phases ago), prefetch plane PN into S
#define PH(SP, S, PN) do {                                                    \
    BAR();                      /* all waves done reading previous plane */   \
    STAGE_WRITE(S);                                                           \
    BAR();                      /* staged writes visible */                   \
    PREFETCH(S, PN);                                                          \
    ROWPASS(0, SP, 0); ROWPASS(0, SP, 1); ROWPASS(0, SP, 2);                  \
    ROWPASS(1, SP, 0); ROWPASS(1, SP, 1); ROWPASS(1, SP, 2);                  \
} while (0)

#define PH_M(SP, S, PN) do {                                                  \
    BAR();                                                                    \
    STAGE_WRITE(S);                                                           \
    BAR();                                                                    \
    PREFETCH_M(S, PN);                                                        \
    ROWPASS(0, SP, 0); ROWPASS(0, SP, 1); ROWPASS(0, SP, 2);                  \
    ROWPASS(1, SP, 0); ROWPASS(1, SP, 1); ROWPASS(1, SP, 2);                  \
} while (0)

#define PH_L(SP, S) do {                                                      \
    BAR();                                                                    \
    STAGE_WRITE(S);                                                           \
    BAR();                                                                    \
    ROWPASS(0, SP, 0); ROWPASS(0, SP, 1); ROWPASS(0, SP, 2);                  \
    ROWPASS(1, SP, 0); ROWPASS(1, SP, 1); ROWPASS(1, SP, 2);                  \
} while (0)

#define EDGEPK(T, SM, SC, SP, EA, E2) do {                                    \
    const v2f   gxA_ = (qa[T][SM][2] + qa[T][SP][2] + 2.f * qa[T][SC][2]) * 0.25f; \
    const float gx2_ = (qc[T][SM][2] + qc[T][SP][2] + 2.f * qc[T][SC][2]) * 0.25f; \
    const v2f   gyA_ = (qa[T][SM][1] + qa[T][SP][1] + 2.f * qa[T][SC][1]) * 0.25f; \
    const float gy2_ = (qc[T][SM][1] + qc[T][SP][1] + 2.f * qc[T][SC][1]) * 0.25f; \
    const v2f   gzA_ = qa[T][SP][0] - qa[T][SM][0];                           \
    const float gz2_ = qc[T][SP][0] - qc[T][SM][0];                           \
    const v2f   dA_ = gxA_ * gxA_ + gyA_ * gyA_ + gzA_ * gzA_ + 1e-8f;        \
    const float d2_ = gx2_ * gx2_ + gy2_ * gy2_ + gz2_ * gz2_ + 1e-8f;        \
    EA = mk2(sqrtf(dA_.x), sqrtf(dA_.y));                                     \
    E2 = sqrtf(d2_);                                                          \
} while (0)

#define EMIT(SM, SC, SP) do {                                                 \
    v2f eA0_, eA1_; float e20_, e21_;                                         \
    EDGEPK(0, SM, SC, SP, eA0_, e20_);                                        \
    EDGEPK(1, SM, SC, SP, eA1_, e21_);                                        \
    const v2f dfA_ = eA0_ - eA1_;                                             \
    accA += mk2(fabsf(dfA_.x), fabsf(dfA_.y));                                \
    acc2 += fabsf(e20_ - e21_);                                               \
} while (0)

    // 18 phases k=0..17: plane d0-1+k, slot k%3, reg-set parity k%2.
    // Phase k prefetches plane d0+1+k (consumed at phase k+2) -> 2-deep.
    PREFETCH_M(A, d0 - 1);
    PREFETCH(B, d0);
    PH(0, A, d0 + 1);                         // k=0
    PH(1, B, d0 + 2);                         // k=1
    for (int gg = 0; gg < 2; ++gg) {          // k=2..13
        const int pp = d0 + 6 * gg;
        PH(2, A, pp + 3);  EMIT(0, 1, 2);
        PH(0, B, pp + 4);  EMIT(1, 2, 0);
        PH(1, A, pp + 5);  EMIT(2, 0, 1);
        PH(2, B, pp + 6);  EMIT(0, 1, 2);
        PH(0, A, pp + 7);  EMIT(1, 2, 0);
        PH(1, B, pp + 8);  EMIT(2, 0, 1);
    }
    PH(2, A, d0 + 15);    EMIT(0, 1, 2);      // k=14
    PH_M(0, B, d0 + 16);  EMIT(1, 2, 0);      // k=15 (plane d0+16 may be OOB)
    PH_L(1, A);           EMIT(2, 0, 1);      // k=16
    PH_L(2, B);           EMIT(0, 1, 2);      // k=17

#undef RPTR
#undef PREFETCH
#undef PREFETCH_M
#undef STAGE_WRITE
#undef ROWPASS
#undef BAR
#undef PH
#undef PH_M
#undef PH_L
#undef EDGEPK
#undef EMIT

    // wave reduce -> block reduce -> one atomic per block
    float acc = accA.x + accA.y + acc2;
    #pragma unroll
    for (int off = 32; off > 0; off >>= 1)
        acc += __shfl_down(acc, off, 64);
    if (lane == 0) wsum[wid] = acc;
    __syncthreads();
    if (threadIdx.x == 0) {
        const float invN = 1.f / (float)((long long)NB * ND * NH * NW);
        atomicAdd(out, (wsum[0] + wsum[1] + wsum[2] + wsum[3]) * invN);
    }
}

} // namespace

extern "C" void kernel_launch(void* const* d_in, const int* in_sizes, int n_in,
                              void* d_out, int out_size, void* d_ws, size_t ws_size,
                              hipStream_t stream) {
    const float* pred = (const float*)d_in[0];
    const float* targ = (const float*)d_in[1];
    float* out = (float*)d_out;
    (void)in_sizes; (void)n_in; (void)out_size; (void)d_ws; (void)ws_size;

    hipMemsetAsync(out, 0, sizeof(float), stream);

    dim3 grid(ND / CD, NH / 4, NB);   // (8, 48, 4) = 1536 blocks, 6/CU
    dim3 block(256);
    edge_loss3d<<<grid, block, 0, stream>>>(pred, targ, out);
}